// Round 1
// baseline (99.713 us; speedup 1.0000x reference)
//
#include <hip/hip_runtime.h>
#include <hip/hip_bf16.h>

#define N 4096
#define D 768

typedef __bf16 bf16x8 __attribute__((ext_vector_type(8)));
typedef float f32x4 __attribute__((ext_vector_type(4)));

typedef __attribute__((address_space(3))) unsigned int as3_uint;
typedef const __attribute__((address_space(1))) unsigned int as1_uint;

__device__ __forceinline__ void gload16(const void* g, void* l) {
    __builtin_amdgcn_global_load_lds((as1_uint*)g, (as3_uint*)l, 16, 0, 0);
}

// ---------------- normalize: f32 [N][D] -> bf16 [N][D], row L2-normalized ----
__global__ __launch_bounds__(256) void norm4(const float* __restrict__ x0,
                                             const float* __restrict__ x1,
                                             const float* __restrict__ x2,
                                             const float* __restrict__ x3,
                                             __hip_bfloat16* __restrict__ o) {
    int a = blockIdx.y;
    const float* x = (a == 0) ? x0 : (a == 1) ? x1 : (a == 2) ? x2 : x3;
    __hip_bfloat16* out = o + (size_t)a * N * D;
    int row = blockIdx.x;
    const float* xr = x + (size_t)row * D;
    int t = threadIdx.x;
    float v0 = xr[t], v1 = xr[t + 256], v2 = xr[t + 512];
    float ss = v0 * v0 + v1 * v1 + v2 * v2;
    #pragma unroll
    for (int m = 1; m < 64; m <<= 1) ss += __shfl_xor(ss, m);
    __shared__ float red[4];
    int lane = t & 63, wid = t >> 6;
    if (lane == 0) red[wid] = ss;
    __syncthreads();
    float tot = red[0] + red[1] + red[2] + red[3];
    float scale = 1.0f / fmaxf(sqrtf(tot), 1e-8f);
    __hip_bfloat16* orow = out + (size_t)row * D;
    orow[t]       = __float2bfloat16(v0 * scale);
    orow[t + 256] = __float2bfloat16(v1 * scale);
    orow[t + 512] = __float2bfloat16(v2 * scale);
}

// ---------------- fused dual-GEMM + softmax-KL partial stats -----------------
// Tile: BM=BN=128, BK=32. 256 threads = 4 waves (2x2), wave tile 64x64.
// Per (ib,jb) block writes partial[jb][row][4] = {Zs, Zt, Ws, Wt} sums over
// its 128 columns.

__device__ __forceinline__ void stage_tile(const __hip_bfloat16* __restrict__ src,
                                           int r0, int k0, char* lds_tile, int t) {
    int row = t >> 2;                 // 0..63
    int clin = (t & 3) << 4;          // 0,16,32,48 bytes within 64B row
    const char* g0 = (const char*)src + ((size_t)(r0 + row) * D + k0) * 2 + clin;
    const char* g1 = (const char*)src + ((size_t)(r0 + row + 64) * D + k0) * 2 + clin;
    gload16(g0, lds_tile + t * 16);
    gload16(g1, lds_tile + 4096 + t * 16);
}

__device__ __forceinline__ bf16x8 lds_frag(const char* tile, int row, int lane) {
    int addr = row * 64 + ((lane >> 4) << 4);
    return *(const bf16x8*)(tile + addr);
}

__global__ __launch_bounds__(256, 2) void fused_gemm(
        const __hip_bfloat16* __restrict__ Xs, const __hip_bfloat16* __restrict__ Ys,
        const __hip_bfloat16* __restrict__ Xt, const __hip_bfloat16* __restrict__ Yt,
        float* __restrict__ partial) {
    __shared__ __align__(16) char smem[32768];
    int t = threadIdx.x;
    int jb = blockIdx.x, ib = blockIdx.y;
    int i0 = ib * 128, j0 = jb * 128;
    int lane = t & 63, wid = t >> 6;
    int wm = wid >> 1, wn = wid & 1;

    f32x4 acc_s[4][4] = {};
    f32x4 acc_t[4][4] = {};

    char* As = smem;
    char* At = smem + 8192;
    char* Bs = smem + 16384;
    char* Bt = smem + 24576;

    for (int kt = 0; kt < D / 32; ++kt) {
        int k0 = kt * 32;
        __syncthreads();   // protect previous iteration's LDS reads
        stage_tile(Xs, i0, k0, As, t);
        stage_tile(Xt, i0, k0, At, t);
        stage_tile(Ys, j0, k0, Bs, t);
        stage_tile(Yt, j0, k0, Bt, t);
        __syncthreads();   // staging complete (vmcnt(0) before s_barrier)

        bf16x8 a_s[4], a_t[4], b_s[4], b_t[4];
        int rA = wm * 64 + (lane & 15);
        int rB = wn * 64 + (lane & 15);
        #pragma unroll
        for (int m = 0; m < 4; ++m) {
            a_s[m] = lds_frag(As, rA + m * 16, lane);
            a_t[m] = lds_frag(At, rA + m * 16, lane);
        }
        #pragma unroll
        for (int n = 0; n < 4; ++n) {
            b_s[n] = lds_frag(Bs, rB + n * 16, lane);
            b_t[n] = lds_frag(Bt, rB + n * 16, lane);
        }
        #pragma unroll
        for (int m = 0; m < 4; ++m)
            #pragma unroll
            for (int n = 0; n < 4; ++n) {
                acc_s[m][n] = __builtin_amdgcn_mfma_f32_16x16x32_bf16(a_s[m], b_s[n], acc_s[m][n], 0, 0, 0);
                acc_t[m][n] = __builtin_amdgcn_mfma_f32_16x16x32_bf16(a_t[m], b_t[n], acc_t[m][n], 0, 0, 0);
            }
    }

    // ---- epilogue: per-row partial stats over this block's 128 columns ----
    __syncthreads();                 // all LDS reads done before smem reuse
    float* part = (float*)smem;      // [2 wn][128 rows][4 stats]
    int g = lane >> 4, cl = lane & 15;

    #pragma unroll
    for (int m = 0; m < 4; ++m) {
        float st[4][4];              // [reg][stat]
        #pragma unroll
        for (int r = 0; r < 4; ++r) { st[r][0] = 0.f; st[r][1] = 0.f; st[r][2] = 0.f; st[r][3] = 0.f; }
        #pragma unroll
        for (int n = 0; n < 4; ++n)
            #pragma unroll
            for (int r = 0; r < 4; ++r) {
                float ls = 10.0f * acc_s[m][n][r];
                float lt = 10.0f * acc_t[m][n][r];
                float es = __expf(ls - 10.0f);
                float et = __expf(lt - 10.0f);
                st[r][0] += es;
                st[r][1] += et;
                st[r][2] += es * (ls - lt);
                st[r][3] += et * (lt - ls);
            }
        #pragma unroll
        for (int r = 0; r < 4; ++r)
            #pragma unroll
            for (int s = 0; s < 4; ++s) {
                float v = st[r][s];
                v += __shfl_xor(v, 1);
                v += __shfl_xor(v, 2);
                v += __shfl_xor(v, 4);
                v += __shfl_xor(v, 8);
                st[r][s] = v;
            }
        if (cl == 0) {
            int row = wm * 64 + m * 16 + g * 4;
            #pragma unroll
            for (int r = 0; r < 4; ++r)
                #pragma unroll
                for (int s = 0; s < 4; ++s)
                    part[(wn * 128 + row + r) * 4 + s] = st[r][s];
        }
    }
    __syncthreads();
    #pragma unroll
    for (int q = 0; q < 2; ++q) {
        int idx = t + q * 256;       // 512 slots = 128 rows x 4 stats
        int row = idx >> 2, s = idx & 3;
        float v = part[(0 * 128 + row) * 4 + s] + part[(1 * 128 + row) * 4 + s];
        partial[((size_t)jb * N + (i0 + row)) * 4 + s] = v;
    }
}

// ---------------- per-row finalize + block partial sums ----------------------
__global__ __launch_bounds__(256) void reduce_rows(const float* __restrict__ partial,
                                                   float* __restrict__ blocksum) {
    int row = blockIdx.x * 256 + threadIdx.x;
    float zs = 0.f, zt = 0.f, ws = 0.f, wt = 0.f;
    for (int jb = 0; jb < 32; ++jb) {
        const float* p = partial + ((size_t)jb * N + row) * 4;
        zs += p[0]; zt += p[1]; ws += p[2]; wt += p[3];
    }
    float ls_row = wt / zt - logf(zt) + logf(zs);   // sum_j q_t (log q_t - log q_s)
    float lt_row = ws / zs - logf(zs) + logf(zt);   // sum_j q_s (log q_s - log q_t)
    #pragma unroll
    for (int m = 1; m < 64; m <<= 1) {
        ls_row += __shfl_xor(ls_row, m);
        lt_row += __shfl_xor(lt_row, m);
    }
    __shared__ float rs[4], rt[4];
    int lane = threadIdx.x & 63, wid = threadIdx.x >> 6;
    if (lane == 0) { rs[wid] = ls_row; rt[wid] = lt_row; }
    __syncthreads();
    if (threadIdx.x == 0) {
        blocksum[blockIdx.x * 2]     = rs[0] + rs[1] + rs[2] + rs[3];
        blocksum[blockIdx.x * 2 + 1] = rt[0] + rt[1] + rt[2] + rt[3];
    }
}

__global__ void final_reduce(const float* __restrict__ blocksum, float* __restrict__ out) {
    float a = 0.f, b = 0.f;
    if (threadIdx.x < 16) { a = blocksum[threadIdx.x * 2]; b = blocksum[threadIdx.x * 2 + 1]; }
    #pragma unroll
    for (int m = 1; m < 16; m <<= 1) { a += __shfl_xor(a, m); b += __shfl_xor(b, m); }
    if (threadIdx.x == 0) {
        const float inv = 1.0f / 16777216.0f;   // 1/N^2
        out[0] = a * inv;
        out[1] = b * inv;
    }
}

extern "C" void kernel_launch(void* const* d_in, const int* in_sizes, int n_in,
                              void* d_out, int out_size, void* d_ws, size_t ws_size,
                              hipStream_t stream) {
    const float* zxs = (const float*)d_in[0];
    const float* zys = (const float*)d_in[1];
    const float* zxt = (const float*)d_in[2];
    const float* zyt = (const float*)d_in[3];

    char* ws = (char*)d_ws;
    const size_t A = (size_t)N * D * 2;               // bytes per bf16 array
    __hip_bfloat16* nb = (__hip_bfloat16*)ws;         // 4 normalized bf16 arrays
    float* partial  = (float*)(ws + 4 * A);           // [32][N][4] f32 = 2 MB
    float* blocksum = (float*)(ws + 4 * A + (size_t)32 * N * 4 * sizeof(float));

    norm4<<<dim3(N, 4), 256, 0, stream>>>(zxs, zys, zxt, zyt, nb);

    const __hip_bfloat16* Xs = nb;
    const __hip_bfloat16* Ys = nb + (size_t)N * D;
    const __hip_bfloat16* Xt = nb + 2 * (size_t)N * D;
    const __hip_bfloat16* Yt = nb + 3 * (size_t)N * D;
    fused_gemm<<<dim3(32, 32), 256, 0, stream>>>(Xs, Ys, Xt, Yt, partial);

    reduce_rows<<<16, 256, 0, stream>>>(partial, blocksum);
    final_reduce<<<1, 64, 0, stream>>>(blocksum, (float*)d_out);
}

// Round 2
// 95.309 us; speedup vs baseline: 1.0462x; 1.0462x over previous
//
#include <hip/hip_runtime.h>
#include <hip/hip_bf16.h>

#define N 4096
#define D 768

typedef __bf16 bf16x8 __attribute__((ext_vector_type(8)));
typedef float f32x4 __attribute__((ext_vector_type(4)));

typedef __attribute__((address_space(3))) unsigned int as3_uint;
typedef const __attribute__((address_space(1))) unsigned int as1_uint;

__device__ __forceinline__ void gload16(const void* g, void* l) {
    __builtin_amdgcn_global_load_lds((as1_uint*)g, (as3_uint*)l, 16, 0, 0);
}

// ---------------- normalize: f32 [N][D] -> bf16 [N][D], row L2-normalized ----
__global__ __launch_bounds__(256) void norm4(const float* __restrict__ x0,
                                             const float* __restrict__ x1,
                                             const float* __restrict__ x2,
                                             const float* __restrict__ x3,
                                             __hip_bfloat16* __restrict__ o) {
    int a = blockIdx.y;
    const float* x = (a == 0) ? x0 : (a == 1) ? x1 : (a == 2) ? x2 : x3;
    __hip_bfloat16* out = o + (size_t)a * N * D;
    int row = blockIdx.x;
    const float* xr = x + (size_t)row * D;
    int t = threadIdx.x;
    float v0 = xr[t], v1 = xr[t + 256], v2 = xr[t + 512];
    float ss = v0 * v0 + v1 * v1 + v2 * v2;
    #pragma unroll
    for (int m = 1; m < 64; m <<= 1) ss += __shfl_xor(ss, m);
    __shared__ float red[4];
    int lane = t & 63, wid = t >> 6;
    if (lane == 0) red[wid] = ss;
    __syncthreads();
    float tot = red[0] + red[1] + red[2] + red[3];
    float scale = 1.0f / fmaxf(sqrtf(tot), 1e-8f);
    __hip_bfloat16* orow = out + (size_t)row * D;
    orow[t]       = __float2bfloat16(v0 * scale);
    orow[t + 256] = __float2bfloat16(v1 * scale);
    orow[t + 512] = __float2bfloat16(v2 * scale);
}

// ---------------- fused dual-GEMM + softmax-KL partial stats -----------------
// Tile: BM=BN=128, BK=32. 256 threads = 4 waves (2x2), wave tile 64x64.
// Double-buffered LDS, prefetch-next-before-compute, ONE barrier per K-step.
// Per (ib,jb) block writes partial[jb][row][4] = {Zs, Zt, Ws, Wt} sums over
// its 128 columns.

__device__ __forceinline__ void stage_tile(const __hip_bfloat16* __restrict__ src,
                                           int r0, int k0, char* lds_tile, int t) {
    int row = t >> 2;                 // 0..63
    int clin = (t & 3) << 4;          // 0,16,32,48 bytes within 64B row
    const char* g0 = (const char*)src + ((size_t)(r0 + row) * D + k0) * 2 + clin;
    const char* g1 = (const char*)src + ((size_t)(r0 + row + 64) * D + k0) * 2 + clin;
    gload16(g0, lds_tile + t * 16);
    gload16(g1, lds_tile + 4096 + t * 16);
}

__device__ __forceinline__ bf16x8 lds_frag(const char* tile, int row, int lane) {
    int addr = row * 64 + ((lane >> 4) << 4);
    return *(const bf16x8*)(tile + addr);
}

__global__ __launch_bounds__(256, 2) void fused_gemm(
        const __hip_bfloat16* __restrict__ Xs, const __hip_bfloat16* __restrict__ Ys,
        const __hip_bfloat16* __restrict__ Xt, const __hip_bfloat16* __restrict__ Yt,
        float* __restrict__ partial) {
    __shared__ __align__(16) char smem[65536];
    int t = threadIdx.x;
    int jb = blockIdx.x, ib = blockIdx.y;
    int i0 = ib * 128, j0 = jb * 128;
    int lane = t & 63, wid = t >> 6;
    int wm = wid >> 1, wn = wid & 1;

    f32x4 acc_s[4][4] = {};
    f32x4 acc_t[4][4] = {};

    // buffer b at smem + b*32768; tiles As,At,Bs,Bt at +0,+8192,+16384,+24576
    #define STAGE(buf, kt)  do {                                            \
        char* base = smem + (buf) * 32768;                                  \
        int k0 = (kt) * 32;                                                 \
        stage_tile(Xs, i0, k0, base,         t);                            \
        stage_tile(Xt, i0, k0, base + 8192,  t);                            \
        stage_tile(Ys, j0, k0, base + 16384, t);                            \
        stage_tile(Yt, j0, k0, base + 24576, t);                            \
    } while (0)

    STAGE(0, 0);
    __syncthreads();                  // drains vmcnt(0): buf0 ready
    int cur = 0;

    int rA = wm * 64 + (lane & 15);
    int rB = wn * 64 + (lane & 15);

    for (int kt = 0; kt < D / 32; ++kt) {
        // issue next K-tile's loads first — they fly during ds_read + MFMA
        if (kt < D / 32 - 1) STAGE(cur ^ 1, kt + 1);

        char* As = smem + cur * 32768;
        char* At = As + 8192;
        char* Bs = As + 16384;
        char* Bt = As + 24576;

        bf16x8 a_s[4], a_t[4], b_s[4], b_t[4];
        #pragma unroll
        for (int m = 0; m < 4; ++m) {
            a_s[m] = lds_frag(As, rA + m * 16, lane);
            a_t[m] = lds_frag(At, rA + m * 16, lane);
        }
        #pragma unroll
        for (int n = 0; n < 4; ++n) {
            b_s[n] = lds_frag(Bs, rB + n * 16, lane);
            b_t[n] = lds_frag(Bt, rB + n * 16, lane);
        }
        #pragma unroll
        for (int m = 0; m < 4; ++m)
            #pragma unroll
            for (int n = 0; n < 4; ++n) {
                acc_s[m][n] = __builtin_amdgcn_mfma_f32_16x16x32_bf16(a_s[m], b_s[n], acc_s[m][n], 0, 0, 0);
                acc_t[m][n] = __builtin_amdgcn_mfma_f32_16x16x32_bf16(a_t[m], b_t[n], acc_t[m][n], 0, 0, 0);
            }

        // one barrier per K-step: drains vmcnt (next buf staged) + lgkmcnt
        // (this buf's reads done, safe to overwrite next iteration)
        __syncthreads();
        cur ^= 1;
    }
    #undef STAGE

    // ---- epilogue: per-row partial stats over this block's 128 columns ----
    float* part = (float*)smem;      // [2 wn][128 rows][4 stats]
    int g = lane >> 4, cl = lane & 15;

    #pragma unroll
    for (int m = 0; m < 4; ++m) {
        float st[4][4];              // [reg][stat]
        #pragma unroll
        for (int r = 0; r < 4; ++r) { st[r][0] = 0.f; st[r][1] = 0.f; st[r][2] = 0.f; st[r][3] = 0.f; }
        #pragma unroll
        for (int n = 0; n < 4; ++n)
            #pragma unroll
            for (int r = 0; r < 4; ++r) {
                float ls = 10.0f * acc_s[m][n][r];
                float lt = 10.0f * acc_t[m][n][r];
                float es = __expf(ls - 10.0f);
                float et = __expf(lt - 10.0f);
                st[r][0] += es;
                st[r][1] += et;
                st[r][2] += es * (ls - lt);
                st[r][3] += et * (lt - ls);
            }
        #pragma unroll
        for (int r = 0; r < 4; ++r)
            #pragma unroll
            for (int s = 0; s < 4; ++s) {
                float v = st[r][s];
                v += __shfl_xor(v, 1);
                v += __shfl_xor(v, 2);
                v += __shfl_xor(v, 4);
                v += __shfl_xor(v, 8);
                st[r][s] = v;
            }
        if (cl == 0) {
            int row = wm * 64 + m * 16 + g * 4;
            #pragma unroll
            for (int r = 0; r < 4; ++r)
                #pragma unroll
                for (int s = 0; s < 4; ++s)
                    part[(wn * 128 + row + r) * 4 + s] = st[r][s];
        }
    }
    __syncthreads();
    #pragma unroll
    for (int q = 0; q < 2; ++q) {
        int idx = t + q * 256;       // 512 slots = 128 rows x 4 stats
        int row = idx >> 2, s = idx & 3;
        float v = part[(0 * 128 + row) * 4 + s] + part[(1 * 128 + row) * 4 + s];
        partial[((size_t)jb * N + (i0 + row)) * 4 + s] = v;
    }
}

// ---------------- per-row finalize + block partial sums ----------------------
__global__ __launch_bounds__(256) void reduce_rows(const float* __restrict__ partial,
                                                   float* __restrict__ blocksum) {
    int row = blockIdx.x * 256 + threadIdx.x;
    float zs = 0.f, zt = 0.f, ws = 0.f, wt = 0.f;
    for (int jb = 0; jb < 32; ++jb) {
        const float* p = partial + ((size_t)jb * N + row) * 4;
        zs += p[0]; zt += p[1]; ws += p[2]; wt += p[3];
    }
    float ls_row = wt / zt - logf(zt) + logf(zs);   // sum_j q_t (log q_t - log q_s)
    float lt_row = ws / zs - logf(zs) + logf(zt);   // sum_j q_s (log q_s - log q_t)
    #pragma unroll
    for (int m = 1; m < 64; m <<= 1) {
        ls_row += __shfl_xor(ls_row, m);
        lt_row += __shfl_xor(lt_row, m);
    }
    __shared__ float rs[4], rt[4];
    int lane = threadIdx.x & 63, wid = threadIdx.x >> 6;
    if (lane == 0) { rs[wid] = ls_row; rt[wid] = lt_row; }
    __syncthreads();
    if (threadIdx.x == 0) {
        blocksum[blockIdx.x * 2]     = rs[0] + rs[1] + rs[2] + rs[3];
        blocksum[blockIdx.x * 2 + 1] = rt[0] + rt[1] + rt[2] + rt[3];
    }
}

__global__ void final_reduce(const float* __restrict__ blocksum, float* __restrict__ out) {
    float a = 0.f, b = 0.f;
    if (threadIdx.x < 16) { a = blocksum[threadIdx.x * 2]; b = blocksum[threadIdx.x * 2 + 1]; }
    #pragma unroll
    for (int m = 1; m < 16; m <<= 1) { a += __shfl_xor(a, m); b += __shfl_xor(b, m); }
    if (threadIdx.x == 0) {
        const float inv = 1.0f / 16777216.0f;   // 1/N^2
        out[0] = a * inv;
        out[1] = b * inv;
    }
}

extern "C" void kernel_launch(void* const* d_in, const int* in_sizes, int n_in,
                              void* d_out, int out_size, void* d_ws, size_t ws_size,
                              hipStream_t stream) {
    const float* zxs = (const float*)d_in[0];
    const float* zys = (const float*)d_in[1];
    const float* zxt = (const float*)d_in[2];
    const float* zyt = (const float*)d_in[3];

    char* ws = (char*)d_ws;
    const size_t A = (size_t)N * D * 2;               // bytes per bf16 array
    __hip_bfloat16* nb = (__hip_bfloat16*)ws;         // 4 normalized bf16 arrays
    float* partial  = (float*)(ws + 4 * A);           // [32][N][4] f32 = 2 MB
    float* blocksum = (float*)(ws + 4 * A + (size_t)32 * N * 4 * sizeof(float));

    norm4<<<dim3(N, 4), 256, 0, stream>>>(zxs, zys, zxt, zyt, nb);

    const __hip_bfloat16* Xs = nb;
    const __hip_bfloat16* Ys = nb + (size_t)N * D;
    const __hip_bfloat16* Xt = nb + 2 * (size_t)N * D;
    const __hip_bfloat16* Yt = nb + 3 * (size_t)N * D;
    fused_gemm<<<dim3(32, 32), 256, 0, stream>>>(Xs, Ys, Xt, Yt, partial);

    reduce_rows<<<16, 256, 0, stream>>>(partial, blocksum);
    final_reduce<<<1, 64, 0, stream>>>(blocksum, (float*)d_out);
}